// Round 7
// baseline (782.230 us; speedup 1.0000x reference)
//
#include <hip/hip_runtime.h>

#define NA_ 131072
#define NN  262144
#define EE  1048576
#define RR  4
#define EPS_ 1e-5f

typedef unsigned short ushort_t;
typedef unsigned int uint_t;
typedef __attribute__((ext_vector_type(8))) short bf16x8;
typedef __attribute__((ext_vector_type(4))) float f32x4;

__device__ __forceinline__ float bf2f(uint_t u16) {
    return __uint_as_float(u16 << 16);
}
__device__ __forceinline__ uint_t f2bf(float f) {
    uint_t x = __float_as_uint(f);
    return (x + 0x7fffu + ((x >> 16) & 1u)) >> 16;   // RNE
}

// ---------------------------------------------------------------------------
// Input projection GEMM: C[M x 128] = relu(A[M x 64] @ B + b)
// ---------------------------------------------------------------------------
__global__ __launch_bounds__(256) void proj_gemm(const float* __restrict__ A,
                                                 const short* __restrict__ Btg,
                                                 const float* __restrict__ bias,
                                                 ushort_t* __restrict__ C) {
    const int K = 64;
    __shared__ short As[128][K + 8];
    __shared__ short Bs[128][K + 8];
    const int tid  = threadIdx.x;
    const int lane = tid & 63;
    const int l15  = lane & 15;
    const int q    = lane >> 4;
    const int wv   = tid >> 6;
    const int wr   = (wv >> 1) * 64;
    const int wc   = (wv & 1) * 64;
    const size_t blockRow = (size_t)blockIdx.x * 128;

    #pragma unroll
    for (int it = 0; it < 4; it++) {
        int sidx = (it * 256 + tid) * 8;
        int row = sidx / K, col = sidx % K;
        const float* Ag = A + (blockRow + row) * K + col;
        float4 v0 = *(const float4*)Ag;
        float4 v1 = *(const float4*)(Ag + 4);
        uint4 u;
        u.x = f2bf(v0.x) | (f2bf(v0.y) << 16);
        u.y = f2bf(v0.z) | (f2bf(v0.w) << 16);
        u.z = f2bf(v1.x) | (f2bf(v1.y) << 16);
        u.w = f2bf(v1.z) | (f2bf(v1.w) << 16);
        *(uint4*)&As[row][col] = u;
        *(uint4*)&Bs[row][col] = *(const uint4*)(Btg + (size_t)row * K + col);
    }
    __syncthreads();

    f32x4 acc[4][4];
    #pragma unroll
    for (int i = 0; i < 4; i++)
        #pragma unroll
        for (int j = 0; j < 4; j++) {
            acc[i][j][0] = 0.f; acc[i][j][1] = 0.f;
            acc[i][j][2] = 0.f; acc[i][j][3] = 0.f;
        }

    #pragma unroll
    for (int kk = 0; kk < 2; kk++) {
        bf16x8 af[4], bfr[4];
        #pragma unroll
        for (int i = 0; i < 4; i++)
            af[i] = *(const bf16x8*)&As[wr + i * 16 + l15][kk * 32 + q * 8];
        #pragma unroll
        for (int j = 0; j < 4; j++)
            bfr[j] = *(const bf16x8*)&Bs[wc + j * 16 + l15][kk * 32 + q * 8];
        #pragma unroll
        for (int i = 0; i < 4; i++)
            #pragma unroll
            for (int j = 0; j < 4; j++)
                acc[i][j] = __builtin_amdgcn_mfma_f32_16x16x32_bf16(
                    af[i], bfr[j], acc[i][j], 0, 0, 0);
    }

    #pragma unroll
    for (int j = 0; j < 4; j++) {
        int gcol = wc + j * 16 + l15;
        float bv = bias[gcol];
        #pragma unroll
        for (int i = 0; i < 4; i++) {
            size_t rbase = blockRow + wr + i * 16 + q * 4;
            #pragma unroll
            for (int r = 0; r < 4; r++) {
                float v = fmaxf(acc[i][j][r] + bv, 0.f);
                C[(rbase + r) * 128 + gcol] = (ushort_t)f2bf(v);
            }
        }
    }
}

// ---------------------------------------------------------------------------
// Weight prep: bf16 fragment-ready [n][k].
// ---------------------------------------------------------------------------
__global__ void prep_weights(const float* __restrict__ Wia,
                             const float* __restrict__ Wiw,
                             const float* __restrict__ Wroot,
                             const float* __restrict__ Wrel,
                             short* __restrict__ wt) {
    int e = blockIdx.x * 256 + threadIdx.x;
    if (e < 8192) {
        int k = e >> 7, n = e & 127;
        wt[n * 64 + k] = (short)f2bf(Wia[e]);
    } else if (e < 16384) {
        int t = e - 8192;
        int k = t >> 7, n = t & 127;
        wt[8192 + n * 64 + k] = (short)f2bf(Wiw[t]);
    } else {
        int t = e - 16384;
        int l = t / 81920;
        int loc = t % 81920;
        int n = loc / 640;
        int k = loc % 640;
        float val;
        if (k < 512) {
            int r = k >> 7, kk = k & 127;
            val = Wrel[(((size_t)l * 4 + r) * 128 + kk) * 128 + n];
        } else {
            int kk = k - 512;
            val = Wroot[((size_t)l * 128 + kk) * 128 + n];
        }
        wt[16384 + (size_t)l * 81920 + n * 640 + k] = (short)f2bf(val);
    }
}

// ---------------------------------------------------------------------------
// CSR build
// ---------------------------------------------------------------------------
__global__ void count_edges(const int* __restrict__ dstv,
                            const int* __restrict__ et,
                            int* __restrict__ cnt) {
    int e = blockIdx.x * 256 + threadIdx.x;
    if (e < EE) atomicAdd(&cnt[(size_t)et[e] * NN + dstv[e]], 1);
}

__global__ void inv_deg(const int* __restrict__ cnt, float* __restrict__ inv,
                        int* __restrict__ deg) {
    int i = blockIdx.x * 256 + threadIdx.x;
    if (i < NN) {
        int c0 = cnt[i], c1 = cnt[NN + i], c2 = cnt[2 * NN + i], c3 = cnt[3 * NN + i];
        inv[i]          = 1.0f / (float)(c0 > 1 ? c0 : 1);
        inv[NN + i]     = 1.0f / (float)(c1 > 1 ? c1 : 1);
        inv[2 * NN + i] = 1.0f / (float)(c2 > 1 ? c2 : 1);
        inv[3 * NN + i] = 1.0f / (float)(c3 > 1 ? c3 : 1);
        deg[i] = c0 + c1 + c2 + c3;
    }
}

__global__ void scan1(const int* __restrict__ deg, int* __restrict__ offs,
                      int* __restrict__ bsum) {
    __shared__ int lds[256];
    int tid = threadIdx.x;
    int i = blockIdx.x * 256 + tid;
    int v = deg[i];
    int incl = v;
    lds[tid] = incl;
    __syncthreads();
    for (int off = 1; off < 256; off <<= 1) {
        int t = (tid >= off) ? lds[tid - off] : 0;
        __syncthreads();
        incl += t;
        lds[tid] = incl;
        __syncthreads();
    }
    offs[i] = incl - v;
    if (tid == 255) bsum[blockIdx.x] = incl;
}

__global__ void scan_bsum(int* __restrict__ bsum) {
    __shared__ int lds[256];
    int tid = threadIdx.x;
    int t0 = bsum[tid * 4 + 0], t1 = bsum[tid * 4 + 1];
    int t2 = bsum[tid * 4 + 2], t3 = bsum[tid * 4 + 3];
    int s = t0 + t1 + t2 + t3;
    int incl = s;
    lds[tid] = incl;
    __syncthreads();
    for (int off = 1; off < 256; off <<= 1) {
        int t = (tid >= off) ? lds[tid - off] : 0;
        __syncthreads();
        incl += t;
        lds[tid] = incl;
        __syncthreads();
    }
    int e = incl - s;
    bsum[tid * 4 + 0] = e;
    bsum[tid * 4 + 1] = e + t0;
    bsum[tid * 4 + 2] = e + t0 + t1;
    bsum[tid * 4 + 3] = e + t0 + t1 + t2;
}

__global__ void scan_add(int* __restrict__ offs, const int* __restrict__ bsum,
                         int* __restrict__ cursor) {
    int i = blockIdx.x * 256 + threadIdx.x;
    int v = offs[i] + bsum[blockIdx.x];
    offs[i] = v;
    cursor[i] = v;
    if (i == 0) offs[NN] = EE;
}

__global__ void place_edges(const int* __restrict__ srcv,
                            const int* __restrict__ dstv,
                            const int* __restrict__ et,
                            int* __restrict__ cursor,
                            uint_t* __restrict__ pk) {
    int e = blockIdx.x * 256 + threadIdx.x;
    if (e < EE) {
        int pos = atomicAdd(&cursor[dstv[e]], 1);
        pk[pos] = (uint_t)srcv[e] | ((uint_t)et[e] << 18);
    }
}

// ---------------------------------------------------------------------------
// Pull aggregation: one wave per dst node, 4-wide batched gathers,
// branchless relation select. M plane-major: plane r = [rowsCap][128] bf16.
// ---------------------------------------------------------------------------
__global__ __launch_bounds__(256) void agg_means(const uint_t* __restrict__ pk,
                                                 const int* __restrict__ offs,
                                                 const ushort_t* __restrict__ hold,
                                                 const float* __restrict__ inv,
                                                 ushort_t* __restrict__ M,
                                                 int lo, int rowsCap) {
    int idx = blockIdx.x * 4 + (threadIdx.x >> 6);
    int d = lo + idx;
    int lane = threadIdx.x & 63;
    int beg = offs[d], end = offs[d + 1];

    float a0x = 0.f, a0y = 0.f, a1x = 0.f, a1y = 0.f;
    float a2x = 0.f, a2y = 0.f, a3x = 0.f, a3y = 0.f;

    auto acc = [&](uint_t p, uint_t hv) {
        float x = bf2f(hv & 0xffffu), y = bf2f(hv >> 16);
        uint_t r = p >> 18;
        a0x += (r == 0) ? x : 0.f;  a0y += (r == 0) ? y : 0.f;
        a1x += (r == 1) ? x : 0.f;  a1y += (r == 1) ? y : 0.f;
        a2x += (r == 2) ? x : 0.f;  a2y += (r == 2) ? y : 0.f;
        a3x += (r == 3) ? x : 0.f;  a3y += (r == 3) ? y : 0.f;
    };

    int e = beg;
    for (; e + 4 <= end; e += 4) {
        uint_t p0 = pk[e], p1 = pk[e + 1], p2 = pk[e + 2], p3 = pk[e + 3];
        uint_t v0 = ((const uint_t*)(hold + (size_t)(p0 & 0x3FFFFu) * 128))[lane];
        uint_t v1 = ((const uint_t*)(hold + (size_t)(p1 & 0x3FFFFu) * 128))[lane];
        uint_t v2 = ((const uint_t*)(hold + (size_t)(p2 & 0x3FFFFu) * 128))[lane];
        uint_t v3 = ((const uint_t*)(hold + (size_t)(p3 & 0x3FFFFu) * 128))[lane];
        acc(p0, v0); acc(p1, v1); acc(p2, v2); acc(p3, v3);
    }
    for (; e < end; e++) {
        uint_t p = pk[e];
        uint_t v = ((const uint_t*)(hold + (size_t)(p & 0x3FFFFu) * 128))[lane];
        acc(p, v);
    }

    float w0 = inv[d], w1 = inv[NN + d], w2 = inv[2 * NN + d], w3 = inv[3 * NN + d];
    uint_t* P = (uint_t*)M;
    size_t planeU = (size_t)rowsCap * 64;
    size_t rowU = (size_t)idx * 64 + lane;
    P[rowU]              = f2bf(a0x * w0) | (f2bf(a0y * w0) << 16);
    P[planeU + rowU]     = f2bf(a1x * w1) | (f2bf(a1y * w1) << 16);
    P[2 * planeU + rowU] = f2bf(a2x * w2) | (f2bf(a2y * w2) << 16);
    P[3 * planeU + rowU] = f2bf(a3x * w3) | (f2bf(a3y * w3) << 16);
}

// ---------------------------------------------------------------------------
// Layer GEMM + LN + ReLU: h_new = relu(LN([M0..3|h] @ Wt + b))
// XOR-swizzled As (conflict-free), B-frags direct from global (L2-resident),
// LDS 34.8 KB -> 4 blocks/CU.
// ---------------------------------------------------------------------------
__global__ __launch_bounds__(256, 4) void layer_gemm_ln(
    const ushort_t* __restrict__ M,
    const ushort_t* __restrict__ hold,
    const short* __restrict__ Btg,       // [128 n][640 k]
    const float* __restrict__ bconv,
    const float* __restrict__ lng,
    const float* __restrict__ lnb,
    ushort_t* __restrict__ hnew,
    int lo, int rowsCap) {
    __shared__ short As[128 * 128];      // XOR-swizzled: chunk c -> c^(row&15)
    __shared__ float lds_s[128][2];
    __shared__ float lds_q[128][2];

    const int tid  = threadIdx.x;
    const int lane = tid & 63;
    const int l15  = lane & 15;
    const int q    = lane >> 4;
    const int wv   = tid >> 6;
    const int wr   = (wv >> 1) * 64;
    const int wc   = (wv & 1) * 64;
    const int blockRowL = blockIdx.x * 128;
    const size_t planeS = (size_t)rowsCap * 128;

    f32x4 acc[4][4];
    #pragma unroll
    for (int i = 0; i < 4; i++)
        #pragma unroll
        for (int j = 0; j < 4; j++) {
            acc[i][j][0] = 0.f; acc[i][j][1] = 0.f;
            acc[i][j][2] = 0.f; acc[i][j][3] = 0.f;
        }

    for (int kc = 0; kc < 5; kc++) {
        __syncthreads();
        // stage A chunk into swizzled LDS (each thread: one 16 B piece x8)
        #pragma unroll
        for (int it = 0; it < 8; it++) {
            int idx = (it * 256 + tid) * 8;
            int row = idx >> 7, col = idx & 127;
            uint4 u;
            if (kc < 4)
                u = *(const uint4*)(M + (size_t)kc * planeS
                                    + (size_t)(blockRowL + row) * 128 + col);
            else
                u = *(const uint4*)(hold + ((size_t)(lo + blockRowL + row) * 128
                                            + col));
            int sw = ((col >> 3) ^ (row & 15)) << 3;
            *(uint4*)&As[row * 128 + sw] = u;
        }
        __syncthreads();
        #pragma unroll
        for (int kk = 0; kk < 4; kk++) {
            bf16x8 af[4], bfr[4];
            #pragma unroll
            for (int i = 0; i < 4; i++) {
                int row = wr + i * 16 + l15;
                int sw = ((kk * 4 + q) ^ l15) << 3;
                af[i] = *(const bf16x8*)&As[row * 128 + sw];
            }
            #pragma unroll
            for (int j = 0; j < 4; j++)
                bfr[j] = *(const bf16x8*)(Btg
                             + (size_t)(wc + j * 16 + l15) * 640
                             + kc * 128 + kk * 32 + q * 8);
            #pragma unroll
            for (int i = 0; i < 4; i++)
                #pragma unroll
                for (int j = 0; j < 4; j++)
                    acc[i][j] = __builtin_amdgcn_mfma_f32_16x16x32_bf16(
                        af[i], bfr[j], acc[i][j], 0, 0, 0);
        }
    }

    // ---- epilogue: + b_conv, LayerNorm, affine, ReLU ----
    float bj[4], gj[4], bbj[4];
    #pragma unroll
    for (int j = 0; j < 4; j++) {
        int col = wc + j * 16 + l15;
        bj[j]  = bconv[col];
        gj[j]  = lng[col];
        bbj[j] = lnb[col];
    }
    #pragma unroll
    for (int i = 0; i < 4; i++)
        #pragma unroll
        for (int j = 0; j < 4; j++)
            #pragma unroll
            for (int r = 0; r < 4; r++) acc[i][j][r] += bj[j];

    float ps[4][4], pq[4][4];
    #pragma unroll
    for (int i = 0; i < 4; i++)
        #pragma unroll
        for (int r = 0; r < 4; r++) {
            float s = 0.f, qq = 0.f;
            #pragma unroll
            for (int j = 0; j < 4; j++) {
                float v = acc[i][j][r];
                s += v;
                qq += v * v;
            }
            ps[i][r] = s;
            pq[i][r] = qq;
        }
    #pragma unroll
    for (int m = 1; m <= 8; m <<= 1)
        #pragma unroll
        for (int i = 0; i < 4; i++)
            #pragma unroll
            for (int r = 0; r < 4; r++) {
                ps[i][r] += __shfl_xor(ps[i][r], m);
                pq[i][r] += __shfl_xor(pq[i][r], m);
            }

    if (l15 == 0) {
        #pragma unroll
        for (int i = 0; i < 4; i++)
            #pragma unroll
            for (int r = 0; r < 4; r++) {
                int row = wr + i * 16 + q * 4 + r;
                lds_s[row][wv & 1] = ps[i][r];
                lds_q[row][wv & 1] = pq[i][r];
            }
    }
    __syncthreads();

    #pragma unroll
    for (int i = 0; i < 4; i++)
        #pragma unroll
        for (int r = 0; r < 4; r++) {
            int row = wr + i * 16 + q * 4 + r;
            float sum = lds_s[row][0] + lds_s[row][1];
            float sq  = lds_q[row][0] + lds_q[row][1];
            float mu  = sum * (1.0f / 128.0f);
            float var = sq * (1.0f / 128.0f) - mu * mu;
            float rs  = rsqrtf(var + EPS_);
            size_t gr = (size_t)(lo + blockRowL + row) * 128;
            #pragma unroll
            for (int j = 0; j < 4; j++) {
                float v = (acc[i][j][r] - mu) * rs * gj[j] + bbj[j];
                v = fmaxf(v, 0.f);
                hnew[gr + wc + j * 16 + l15] = (ushort_t)f2bf(v);
            }
        }
}

// ---------------------------------------------------------------------------
__global__ __launch_bounds__(256) void head_dot(const ushort_t* __restrict__ Hh,
                                                const float* __restrict__ Wout,
                                                const float* __restrict__ bout,
                                                const float* __restrict__ base,
                                                float* __restrict__ pred) {
    int node = blockIdx.x * 4 + (threadIdx.x >> 6);
    int lane = threadIdx.x & 63;
    uint_t u = ((const uint_t*)(Hh + (size_t)node * 128))[lane];
    float2 w = ((const float2*)Wout)[lane];
    float s = bf2f(u & 0xffffu) * w.x + bf2f(u >> 16) * w.y;
    #pragma unroll
    for (int off = 32; off; off >>= 1) s += __shfl_down(s, off);
    if (lane == 0) pred[node] = s + bout[0] + base[0];
}

// ---------------------------------------------------------------------------
extern "C" void kernel_launch(void* const* d_in, const int* in_sizes, int n_in,
                              void* d_out, int out_size, void* d_ws, size_t ws_size,
                              hipStream_t stream) {
    const float* x_a    = (const float*)d_in[0];
    const float* x_w    = (const float*)d_in[1];
    const int*   eidx   = (const int*)d_in[2];
    const int*   etype  = (const int*)d_in[3];
    const float* W_in_a = (const float*)d_in[4];
    const float* b_in_a = (const float*)d_in[5];
    const float* W_in_w = (const float*)d_in[6];
    const float* b_in_w = (const float*)d_in[7];
    const float* W_rel  = (const float*)d_in[8];
    const float* W_root = (const float*)d_in[9];
    const float* b_conv = (const float*)d_in[10];
    const float* ln_g   = (const float*)d_in[11];
    const float* ln_b   = (const float*)d_in[12];
    const float* W_out  = (const float*)d_in[13];
    const float* b_out  = (const float*)d_in[14];
    const float* base   = (const float*)d_in[15];

    const int* src  = eidx;
    const int* dstv = eidx + EE;

    // ---- workspace: persistent first, then CSR scratch overlaid by M ----
    char* p = (char*)d_ws;
    auto alloc = [&](size_t bytes) {
        char* q = p;
        p += (bytes + 255) & ~(size_t)255;
        return q;
    };
    ushort_t* hA   = (ushort_t*)alloc((size_t)NN * 128 * 2);   // 67.1 MB
    ushort_t* hB   = (ushort_t*)alloc((size_t)NN * 128 * 2);   // 67.1 MB
    float*    inv  = (float*)alloc((size_t)RR * NN * 4);       // 4.2 MB
    uint_t*   pk   = (uint_t*)alloc((size_t)EE * 4);           // 4.2 MB
    int*      offs = (int*)alloc((size_t)(NN + 1) * 4);        // 1.05 MB
    short*    wbuf = (short*)alloc((size_t)180224 * 2);        // 0.36 MB
    char*     scratch = p;                                     // CSR scratch / M
    int*      cnt  = (int*)alloc((size_t)RR * NN * 4);         // dead after CSR
    int*      curs = (int*)alloc((size_t)NN * 4);              // dead after CSR
    int*      bsum = (int*)alloc((size_t)1024 * 4);            // dead after CSR
    ushort_t* M    = (ushort_t*)scratch;                       // overlays scratch

    size_t rem = (ws_size > (size_t)(scratch - (char*)d_ws))
                     ? (ws_size - (size_t)(scratch - (char*)d_ws)) : 0;
    int rowsCap = (int)(rem / 1024);          // 4 planes x 256 B per row
    if (rowsCap > 65536) rowsCap = 65536;     // keep M chunk L3-resident (64 MB)
    rowsCap &= ~127;
    if (rowsCap == 0) rowsCap = 128;          // best effort

    short* wt_ina = wbuf;
    short* wt_inw = wbuf + 8192;
    auto wt_layer = [&](int l) { return wbuf + 16384 + (size_t)l * 81920; };

    // ---- CSR + inv ----
    hipMemsetAsync(cnt, 0, (size_t)RR * NN * sizeof(int), stream);
    count_edges<<<EE / 256, 256, 0, stream>>>(dstv, etype, cnt);
    inv_deg<<<NN / 256, 256, 0, stream>>>(cnt, inv, curs);
    scan1<<<NN / 256, 256, 0, stream>>>(curs, offs, bsum);
    scan_bsum<<<1, 256, 0, stream>>>(bsum);
    scan_add<<<NN / 256, 256, 0, stream>>>(offs, bsum, curs);
    place_edges<<<EE / 256, 256, 0, stream>>>(src, dstv, etype, curs, pk);

    prep_weights<<<704, 256, 0, stream>>>(W_in_a, W_in_w, W_root, W_rel, wbuf);

    // ---- input projections ----
    proj_gemm<<<NA_ / 128, 256, 0, stream>>>(x_a, wt_ina, b_in_a, hA);
    proj_gemm<<<NA_ / 128, 256, 0, stream>>>(x_w, wt_inw, b_in_w,
                                             hA + (size_t)NA_ * 128);

    // ---- layers; layer 2 only needs output rows < NA (head truncation) ----
    ushort_t* hc = hA;
    ushort_t* hn = hB;
    for (int l = 0; l < 2; l++) {
        int Nout = (l == 0) ? NN : NA_;
        for (int lo = 0; lo < Nout; lo += rowsCap) {
            int cr = (Nout - lo < rowsCap) ? (Nout - lo) : rowsCap;
            agg_means<<<cr / 4, 256, 0, stream>>>(pk, offs, hc, inv, M, lo,
                                                  rowsCap);
            layer_gemm_ln<<<cr / 128, 256, 0, stream>>>(
                M, hc, wt_layer(l), b_conv + l * 128, ln_g + l * 128,
                ln_b + l * 128, hn, lo, rowsCap);
        }
        ushort_t* t = hc; hc = hn; hn = t;
    }

    head_dot<<<NA_ / 4, 256, 0, stream>>>(hc, W_out, b_out, base, (float*)d_out);
}

// Round 8
// 633.898 us; speedup vs baseline: 1.2340x; 1.2340x over previous
//
#include <hip/hip_runtime.h>

#define NA_ 131072
#define NN  262144
#define EE  1048576
#define RR  4
#define EPS_ 1e-5f

typedef unsigned short ushort_t;
typedef unsigned int uint_t;
typedef __attribute__((ext_vector_type(8))) short bf16x8;
typedef __attribute__((ext_vector_type(4))) float f32x4;

__device__ __forceinline__ float bf2f(uint_t u16) {
    return __uint_as_float(u16 << 16);
}
__device__ __forceinline__ uint_t f2bf(float f) {
    uint_t x = __float_as_uint(f);
    return (x + 0x7fffu + ((x >> 16) & 1u)) >> 16;   // RNE
}

// async global->LDS DMA, 16 B per lane; lds base must be wave-uniform
__device__ __forceinline__ void gl2lds16(const void* g, void* l) {
    __builtin_amdgcn_global_load_lds(
        (const __attribute__((address_space(1))) void*)g,
        (__attribute__((address_space(3))) void*)l, 16, 0, 0);
}

// ---------------------------------------------------------------------------
// Input projection GEMM: C[M x 128] = relu(A[M x 64] @ B + b)
// ---------------------------------------------------------------------------
__global__ __launch_bounds__(256) void proj_gemm(const float* __restrict__ A,
                                                 const short* __restrict__ Btg,
                                                 const float* __restrict__ bias,
                                                 ushort_t* __restrict__ C) {
    const int K = 64;
    __shared__ short As[128][K + 8];
    __shared__ short Bs[128][K + 8];
    const int tid  = threadIdx.x;
    const int lane = tid & 63;
    const int l15  = lane & 15;
    const int q    = lane >> 4;
    const int wv   = tid >> 6;
    const int wr   = (wv >> 1) * 64;
    const int wc   = (wv & 1) * 64;
    const size_t blockRow = (size_t)blockIdx.x * 128;

    #pragma unroll
    for (int it = 0; it < 4; it++) {
        int sidx = (it * 256 + tid) * 8;
        int row = sidx / K, col = sidx % K;
        const float* Ag = A + (blockRow + row) * K + col;
        float4 v0 = *(const float4*)Ag;
        float4 v1 = *(const float4*)(Ag + 4);
        uint4 u;
        u.x = f2bf(v0.x) | (f2bf(v0.y) << 16);
        u.y = f2bf(v0.z) | (f2bf(v0.w) << 16);
        u.z = f2bf(v1.x) | (f2bf(v1.y) << 16);
        u.w = f2bf(v1.z) | (f2bf(v1.w) << 16);
        *(uint4*)&As[row][col] = u;
        *(uint4*)&Bs[row][col] = *(const uint4*)(Btg + (size_t)row * K + col);
    }
    __syncthreads();

    f32x4 acc[4][4];
    #pragma unroll
    for (int i = 0; i < 4; i++)
        #pragma unroll
        for (int j = 0; j < 4; j++) {
            acc[i][j][0] = 0.f; acc[i][j][1] = 0.f;
            acc[i][j][2] = 0.f; acc[i][j][3] = 0.f;
        }

    #pragma unroll
    for (int kk = 0; kk < 2; kk++) {
        bf16x8 af[4], bfr[4];
        #pragma unroll
        for (int i = 0; i < 4; i++)
            af[i] = *(const bf16x8*)&As[wr + i * 16 + l15][kk * 32 + q * 8];
        #pragma unroll
        for (int j = 0; j < 4; j++)
            bfr[j] = *(const bf16x8*)&Bs[wc + j * 16 + l15][kk * 32 + q * 8];
        #pragma unroll
        for (int i = 0; i < 4; i++)
            #pragma unroll
            for (int j = 0; j < 4; j++)
                acc[i][j] = __builtin_amdgcn_mfma_f32_16x16x32_bf16(
                    af[i], bfr[j], acc[i][j], 0, 0, 0);
    }

    #pragma unroll
    for (int j = 0; j < 4; j++) {
        int gcol = wc + j * 16 + l15;
        float bv = bias[gcol];
        #pragma unroll
        for (int i = 0; i < 4; i++) {
            size_t rbase = blockRow + wr + i * 16 + q * 4;
            #pragma unroll
            for (int r = 0; r < 4; r++) {
                float v = fmaxf(acc[i][j][r] + bv, 0.f);
                C[(rbase + r) * 128 + gcol] = (ushort_t)f2bf(v);
            }
        }
    }
}

// ---------------------------------------------------------------------------
// Weight prep. Input-proj: [n][64]. Layer weights: CHUNK-MAJOR
// [kc][n][128] per layer (kc 0..3 = rel0..3, kc 4 = root) so each 128-k
// chunk is a contiguous 32 KB block for global_load_lds staging.
// ---------------------------------------------------------------------------
__global__ void prep_weights(const float* __restrict__ Wia,
                             const float* __restrict__ Wiw,
                             const float* __restrict__ Wroot,
                             const float* __restrict__ Wrel,
                             short* __restrict__ wt) {
    int e = blockIdx.x * 256 + threadIdx.x;
    if (e < 8192) {
        int k = e >> 7, n = e & 127;
        wt[n * 64 + k] = (short)f2bf(Wia[e]);
    } else if (e < 16384) {
        int t = e - 8192;
        int k = t >> 7, n = t & 127;
        wt[8192 + n * 64 + k] = (short)f2bf(Wiw[t]);
    } else {
        int t = e - 16384;           // 0 .. 163839
        int l = t / 81920;
        int d = t % 81920;           // dst index within layer block
        int kc = d / 16384;
        int rem = d % 16384;
        int n = rem >> 7;
        int kkk = rem & 127;
        float val = (kc < 4)
            ? Wrel[(((size_t)l * 4 + kc) * 128 + kkk) * 128 + n]
            : Wroot[((size_t)l * 128 + kkk) * 128 + n];
        wt[16384 + (size_t)l * 81920 + d] = (short)f2bf(val);
    }
}

// ---------------------------------------------------------------------------
// CSR build
// ---------------------------------------------------------------------------
__global__ void count_edges(const int* __restrict__ dstv,
                            const int* __restrict__ et,
                            int* __restrict__ cnt) {
    int e = blockIdx.x * 256 + threadIdx.x;
    if (e < EE) atomicAdd(&cnt[(size_t)et[e] * NN + dstv[e]], 1);
}

__global__ void inv_deg(const int* __restrict__ cnt, float* __restrict__ inv,
                        int* __restrict__ deg) {
    int i = blockIdx.x * 256 + threadIdx.x;
    if (i < NN) {
        int c0 = cnt[i], c1 = cnt[NN + i], c2 = cnt[2 * NN + i], c3 = cnt[3 * NN + i];
        inv[i]          = 1.0f / (float)(c0 > 1 ? c0 : 1);
        inv[NN + i]     = 1.0f / (float)(c1 > 1 ? c1 : 1);
        inv[2 * NN + i] = 1.0f / (float)(c2 > 1 ? c2 : 1);
        inv[3 * NN + i] = 1.0f / (float)(c3 > 1 ? c3 : 1);
        deg[i] = c0 + c1 + c2 + c3;
    }
}

__global__ void scan1(const int* __restrict__ deg, int* __restrict__ offs,
                      int* __restrict__ bsum) {
    __shared__ int lds[256];
    int tid = threadIdx.x;
    int i = blockIdx.x * 256 + tid;
    int v = deg[i];
    int incl = v;
    lds[tid] = incl;
    __syncthreads();
    for (int off = 1; off < 256; off <<= 1) {
        int t = (tid >= off) ? lds[tid - off] : 0;
        __syncthreads();
        incl += t;
        lds[tid] = incl;
        __syncthreads();
    }
    offs[i] = incl - v;
    if (tid == 255) bsum[blockIdx.x] = incl;
}

__global__ void scan_bsum(int* __restrict__ bsum) {
    __shared__ int lds[256];
    int tid = threadIdx.x;
    int t0 = bsum[tid * 4 + 0], t1 = bsum[tid * 4 + 1];
    int t2 = bsum[tid * 4 + 2], t3 = bsum[tid * 4 + 3];
    int s = t0 + t1 + t2 + t3;
    int incl = s;
    lds[tid] = incl;
    __syncthreads();
    for (int off = 1; off < 256; off <<= 1) {
        int t = (tid >= off) ? lds[tid - off] : 0;
        __syncthreads();
        incl += t;
        lds[tid] = incl;
        __syncthreads();
    }
    int e = incl - s;
    bsum[tid * 4 + 0] = e;
    bsum[tid * 4 + 1] = e + t0;
    bsum[tid * 4 + 2] = e + t0 + t1;
    bsum[tid * 4 + 3] = e + t0 + t1 + t2;
}

__global__ void scan_add(int* __restrict__ offs, const int* __restrict__ bsum,
                         int* __restrict__ cursor) {
    int i = blockIdx.x * 256 + threadIdx.x;
    int v = offs[i] + bsum[blockIdx.x];
    offs[i] = v;
    cursor[i] = v;
    if (i == 0) offs[NN] = EE;
}

__global__ void place_edges(const int* __restrict__ srcv,
                            const int* __restrict__ dstv,
                            const int* __restrict__ et,
                            int* __restrict__ cursor,
                            uint_t* __restrict__ pk) {
    int e = blockIdx.x * 256 + threadIdx.x;
    if (e < EE) {
        int pos = atomicAdd(&cursor[dstv[e]], 1);
        pk[pos] = (uint_t)srcv[e] | ((uint_t)et[e] << 18);
    }
}

// ---------------------------------------------------------------------------
// Pull aggregation: one wave per dst node, 4-wide batched gathers,
// branchless relation select. M plane-major: plane r = [rowsCap][128] bf16.
// ---------------------------------------------------------------------------
__global__ __launch_bounds__(256) void agg_means(const uint_t* __restrict__ pk,
                                                 const int* __restrict__ offs,
                                                 const ushort_t* __restrict__ hold,
                                                 const float* __restrict__ inv,
                                                 ushort_t* __restrict__ M,
                                                 int lo, int rowsCap) {
    int idx = blockIdx.x * 4 + (threadIdx.x >> 6);
    int d = lo + idx;
    int lane = threadIdx.x & 63;
    int beg = offs[d], end = offs[d + 1];

    float a0x = 0.f, a0y = 0.f, a1x = 0.f, a1y = 0.f;
    float a2x = 0.f, a2y = 0.f, a3x = 0.f, a3y = 0.f;

    auto acc = [&](uint_t p, uint_t hv) {
        float x = bf2f(hv & 0xffffu), y = bf2f(hv >> 16);
        uint_t r = p >> 18;
        a0x += (r == 0) ? x : 0.f;  a0y += (r == 0) ? y : 0.f;
        a1x += (r == 1) ? x : 0.f;  a1y += (r == 1) ? y : 0.f;
        a2x += (r == 2) ? x : 0.f;  a2y += (r == 2) ? y : 0.f;
        a3x += (r == 3) ? x : 0.f;  a3y += (r == 3) ? y : 0.f;
    };

    int e = beg;
    for (; e + 4 <= end; e += 4) {
        uint_t p0 = pk[e], p1 = pk[e + 1], p2 = pk[e + 2], p3 = pk[e + 3];
        uint_t v0 = ((const uint_t*)(hold + (size_t)(p0 & 0x3FFFFu) * 128))[lane];
        uint_t v1 = ((const uint_t*)(hold + (size_t)(p1 & 0x3FFFFu) * 128))[lane];
        uint_t v2 = ((const uint_t*)(hold + (size_t)(p2 & 0x3FFFFu) * 128))[lane];
        uint_t v3 = ((const uint_t*)(hold + (size_t)(p3 & 0x3FFFFu) * 128))[lane];
        acc(p0, v0); acc(p1, v1); acc(p2, v2); acc(p3, v3);
    }
    for (; e < end; e++) {
        uint_t p = pk[e];
        uint_t v = ((const uint_t*)(hold + (size_t)(p & 0x3FFFFu) * 128))[lane];
        acc(p, v);
    }

    float w0 = inv[d], w1 = inv[NN + d], w2 = inv[2 * NN + d], w3 = inv[3 * NN + d];
    uint_t* P = (uint_t*)M;
    size_t planeU = (size_t)rowsCap * 64;
    size_t rowU = (size_t)idx * 64 + lane;
    P[rowU]              = f2bf(a0x * w0) | (f2bf(a0y * w0) << 16);
    P[planeU + rowU]     = f2bf(a1x * w1) | (f2bf(a1y * w1) << 16);
    P[2 * planeU + rowU] = f2bf(a2x * w2) | (f2bf(a2y * w2) << 16);
    P[3 * planeU + rowU] = f2bf(a3x * w3) | (f2bf(a3y * w3) << 16);
}

// ---------------------------------------------------------------------------
// Layer GEMM + LN + ReLU: h_new = relu(LN([M0..3|h] @ Wt + b))
// m97-style staging: both A chunk (32 KB contiguous: M plane / h rows) and
// B chunk (32 KB contiguous: chunk-major weights) DMA'd to LDS via
// global_load_lds width=16. 2-barrier K-loop, 5 chunks of K=128.
// ---------------------------------------------------------------------------
__global__ __launch_bounds__(256) void layer_gemm_ln(
    const ushort_t* __restrict__ M,
    const ushort_t* __restrict__ hold,
    const short* __restrict__ Btg,       // [5][128 n][128 k] chunk-major
    const float* __restrict__ bconv,
    const float* __restrict__ lng,
    const float* __restrict__ lnb,
    ushort_t* __restrict__ hnew,
    int lo, int rowsCap) {
    __shared__ short As[128 * 128];      // [row][128 k] row-major
    __shared__ short Bs[128 * 128];      // [n][128 k]  row-major
    __shared__ float lds_s[128][2];
    __shared__ float lds_q[128][2];

    const int tid  = threadIdx.x;
    const int lane = tid & 63;
    const int l15  = lane & 15;
    const int q    = lane >> 4;
    const int wv   = tid >> 6;
    const int wr   = (wv >> 1) * 64;
    const int wc   = (wv & 1) * 64;
    const int blockRowL = blockIdx.x * 128;
    const size_t planeS = (size_t)rowsCap * 128;

    f32x4 acc[4][4];
    #pragma unroll
    for (int i = 0; i < 4; i++)
        #pragma unroll
        for (int j = 0; j < 4; j++) {
            acc[i][j][0] = 0.f; acc[i][j][1] = 0.f;
            acc[i][j][2] = 0.f; acc[i][j][3] = 0.f;
        }

    const int lby = lane << 4;           // lane byte offset (16 B/lane)

    for (int kc = 0; kc < 5; kc++) {
        const char* asrc = (kc < 4)
            ? (const char*)(M + (size_t)kc * planeS + (size_t)blockRowL * 128)
            : (const char*)(hold + (size_t)(lo + blockRowL) * 128);
        const char* bsrc = (const char*)(Btg + (size_t)kc * 16384);
        __syncthreads();   // previous chunk's consumers done
        #pragma unroll
        for (int it = 0; it < 8; it++) {
            int off = it * 4096 + wv * 1024;   // wave-uniform LDS offset
            gl2lds16(asrc + off + lby, (char*)As + off);
            gl2lds16(bsrc + off + lby, (char*)Bs + off);
        }
        __syncthreads();   // drains vmcnt (compiler-inserted) + barrier

        #pragma unroll
        for (int kk = 0; kk < 4; kk++) {
            bf16x8 af[4], bfr[4];
            #pragma unroll
            for (int i = 0; i < 4; i++)
                af[i] = *(const bf16x8*)
                    &As[(wr + i * 16 + l15) * 128 + kk * 32 + q * 8];
            #pragma unroll
            for (int j = 0; j < 4; j++)
                bfr[j] = *(const bf16x8*)
                    &Bs[(wc + j * 16 + l15) * 128 + kk * 32 + q * 8];
            #pragma unroll
            for (int i = 0; i < 4; i++)
                #pragma unroll
                for (int j = 0; j < 4; j++)
                    acc[i][j] = __builtin_amdgcn_mfma_f32_16x16x32_bf16(
                        af[i], bfr[j], acc[i][j], 0, 0, 0);
        }
    }

    // ---- epilogue: + b_conv, LayerNorm, affine, ReLU ----
    float bj[4], gj[4], bbj[4];
    #pragma unroll
    for (int j = 0; j < 4; j++) {
        int col = wc + j * 16 + l15;
        bj[j]  = bconv[col];
        gj[j]  = lng[col];
        bbj[j] = lnb[col];
    }
    #pragma unroll
    for (int i = 0; i < 4; i++)
        #pragma unroll
        for (int j = 0; j < 4; j++)
            #pragma unroll
            for (int r = 0; r < 4; r++) acc[i][j][r] += bj[j];

    float ps[4][4], pq[4][4];
    #pragma unroll
    for (int i = 0; i < 4; i++)
        #pragma unroll
        for (int r = 0; r < 4; r++) {
            float s = 0.f, qq = 0.f;
            #pragma unroll
            for (int j = 0; j < 4; j++) {
                float v = acc[i][j][r];
                s += v;
                qq += v * v;
            }
            ps[i][r] = s;
            pq[i][r] = qq;
        }
    #pragma unroll
    for (int m = 1; m <= 8; m <<= 1)
        #pragma unroll
        for (int i = 0; i < 4; i++)
            #pragma unroll
            for (int r = 0; r < 4; r++) {
                ps[i][r] += __shfl_xor(ps[i][r], m);
                pq[i][r] += __shfl_xor(pq[i][r], m);
            }

    if (l15 == 0) {
        #pragma unroll
        for (int i = 0; i < 4; i++)
            #pragma unroll
            for (int r = 0; r < 4; r++) {
                int row = wr + i * 16 + q * 4 + r;
                lds_s[row][wv & 1] = ps[i][r];
                lds_q[row][wv & 1] = pq[i][r];
            }
    }
    __syncthreads();

    #pragma unroll
    for (int i = 0; i < 4; i++)
        #pragma unroll
        for (int r = 0; r < 4; r++) {
            int row = wr + i * 16 + q * 4 + r;
            float sum = lds_s[row][0] + lds_s[row][1];
            float sq  = lds_q[row][0] + lds_q[row][1];
            float mu  = sum * (1.0f / 128.0f);
            float var = sq * (1.0f / 128.0f) - mu * mu;
            float rs  = rsqrtf(var + EPS_);
            size_t gr = (size_t)(lo + blockRowL + row) * 128;
            #pragma unroll
            for (int j = 0; j < 4; j++) {
                float v = (acc[i][j][r] - mu) * rs * gj[j] + bbj[j];
                v = fmaxf(v, 0.f);
                hnew[gr + wc + j * 16 + l15] = (ushort_t)f2bf(v);
            }
        }
}

// ---------------------------------------------------------------------------
__global__ __launch_bounds__(256) void head_dot(const ushort_t* __restrict__ Hh,
                                                const float* __restrict__ Wout,
                                                const float* __restrict__ bout,
                                                const float* __restrict__ base,
                                                float* __restrict__ pred) {
    int node = blockIdx.x * 4 + (threadIdx.x >> 6);
    int lane = threadIdx.x & 63;
    uint_t u = ((const uint_t*)(Hh + (size_t)node * 128))[lane];
    float2 w = ((const float2*)Wout)[lane];
    float s = bf2f(u & 0xffffu) * w.x + bf2f(u >> 16) * w.y;
    #pragma unroll
    for (int off = 32; off; off >>= 1) s += __shfl_down(s, off);
    if (lane == 0) pred[node] = s + bout[0] + base[0];
}

// ---------------------------------------------------------------------------
extern "C" void kernel_launch(void* const* d_in, const int* in_sizes, int n_in,
                              void* d_out, int out_size, void* d_ws, size_t ws_size,
                              hipStream_t stream) {
    const float* x_a    = (const float*)d_in[0];
    const float* x_w    = (const float*)d_in[1];
    const int*   eidx   = (const int*)d_in[2];
    const int*   etype  = (const int*)d_in[3];
    const float* W_in_a = (const float*)d_in[4];
    const float* b_in_a = (const float*)d_in[5];
    const float* W_in_w = (const float*)d_in[6];
    const float* b_in_w = (const float*)d_in[7];
    const float* W_rel  = (const float*)d_in[8];
    const float* W_root = (const float*)d_in[9];
    const float* b_conv = (const float*)d_in[10];
    const float* ln_g   = (const float*)d_in[11];
    const float* ln_b   = (const float*)d_in[12];
    const float* W_out  = (const float*)d_in[13];
    const float* b_out  = (const float*)d_in[14];
    const float* base   = (const float*)d_in[15];

    const int* src  = eidx;
    const int* dstv = eidx + EE;

    // ---- workspace: persistent first, then CSR scratch overlaid by M ----
    char* p = (char*)d_ws;
    auto alloc = [&](size_t bytes) {
        char* q = p;
        p += (bytes + 255) & ~(size_t)255;
        return q;
    };
    ushort_t* hA   = (ushort_t*)alloc((size_t)NN * 128 * 2);   // 67.1 MB
    ushort_t* hB   = (ushort_t*)alloc((size_t)NN * 128 * 2);   // 67.1 MB
    float*    inv  = (float*)alloc((size_t)RR * NN * 4);       // 4.2 MB
    uint_t*   pk   = (uint_t*)alloc((size_t)EE * 4);           // 4.2 MB
    int*      offs = (int*)alloc((size_t)(NN + 1) * 4);        // 1.05 MB
    short*    wbuf = (short*)alloc((size_t)180224 * 2);        // 0.36 MB
    char*     scratch = p;                                     // CSR scratch / M
    int*      cnt  = (int*)alloc((size_t)RR * NN * 4);         // dead after CSR
    int*      curs = (int*)alloc((size_t)NN * 4);              // dead after CSR
    int*      bsum = (int*)alloc((size_t)1024 * 4);            // dead after CSR
    ushort_t* M    = (ushort_t*)scratch;                       // overlays scratch

    size_t rem = (ws_size > (size_t)(scratch - (char*)d_ws))
                     ? (ws_size - (size_t)(scratch - (char*)d_ws)) : 0;
    int rowsCap = (int)(rem / 1024);          // 4 planes x 256 B per row
    if (rowsCap > 65536) rowsCap = 65536;     // keep M chunk L3-resident (64 MB)
    rowsCap &= ~127;
    if (rowsCap == 0) rowsCap = 128;          // best effort

    short* wt_ina = wbuf;
    short* wt_inw = wbuf + 8192;
    auto wt_layer = [&](int l) { return wbuf + 16384 + (size_t)l * 81920; };

    // ---- CSR + inv ----
    hipMemsetAsync(cnt, 0, (size_t)RR * NN * sizeof(int), stream);
    count_edges<<<EE / 256, 256, 0, stream>>>(dstv, etype, cnt);
    inv_deg<<<NN / 256, 256, 0, stream>>>(cnt, inv, curs);
    scan1<<<NN / 256, 256, 0, stream>>>(curs, offs, bsum);
    scan_bsum<<<1, 256, 0, stream>>>(bsum);
    scan_add<<<NN / 256, 256, 0, stream>>>(offs, bsum, curs);
    place_edges<<<EE / 256, 256, 0, stream>>>(src, dstv, etype, curs, pk);

    prep_weights<<<704, 256, 0, stream>>>(W_in_a, W_in_w, W_root, W_rel, wbuf);

    // ---- input projections ----
    proj_gemm<<<NA_ / 128, 256, 0, stream>>>(x_a, wt_ina, b_in_a, hA);
    proj_gemm<<<NA_ / 128, 256, 0, stream>>>(x_w, wt_inw, b_in_w,
                                             hA + (size_t)NA_ * 128);

    // ---- layers; layer 2 only needs output rows < NA (head truncation) ----
    ushort_t* hc = hA;
    ushort_t* hn = hB;
    for (int l = 0; l < 2; l++) {
        int Nout = (l == 0) ? NN : NA_;
        for (int lo = 0; lo < Nout; lo += rowsCap) {
            int cr = (Nout - lo < rowsCap) ? (Nout - lo) : rowsCap;
            agg_means<<<cr / 4, 256, 0, stream>>>(pk, offs, hc, inv, M, lo,
                                                  rowsCap);
            layer_gemm_ln<<<cr / 128, 256, 0, stream>>>(
                M, hc, wt_layer(l), b_conv + l * 128, ln_g + l * 128,
                ln_b + l * 128, hn, lo, rowsCap);
        }
        ushort_t* t = hc; hc = hn; hn = t;
    }

    head_dot<<<NA_ / 4, 256, 0, stream>>>(hc, W_out, b_out, base, (float*)d_out);
}